// Round 5
// baseline (214.672 us; speedup 1.0000x reference)
//
#include <hip/hip_runtime.h>

#define N_NODES 8192
#define N_EDGES 65536
#define FEAT    136
#define WNUM    3392

typedef __attribute__((ext_vector_type(4))) short s16x4;
typedef __attribute__((ext_vector_type(8))) short s16x8;
typedef __attribute__((ext_vector_type(4))) float f32x4;

__device__ __forceinline__ float b2f(unsigned short h) {
    union { unsigned int u; float f; } v; v.u = ((unsigned int)h) << 16; return v.f;
}
__device__ __forceinline__ unsigned short f2b(float f) {
    union { float f; unsigned int u; } v; v.f = f;
    unsigned int u = v.u;
    unsigned int r = (u + 0x7FFFu + ((u >> 16) & 1u)) >> 16;
    return (unsigned short)r;
}

// total scale for W2 column `col` = 1/sqrt(fan_in) * per-i sub-factor (inv_s3/inv_s2)
__device__ __forceinline__ float wscale(int col) {
    const float inv_s3 = 0.57735026918962576f;
    const float inv_s2 = 0.70710678118654752f;
    if (col < 1536) { int i = col >> 5;          return 0.14433756729740643f * (i < 32 ? 1.f : inv_s3); }
    if (col < 2560) { int i = (col - 1536) >> 4; return 0.125f               * (i >= 48 ? inv_s2 : 1.f); }
    if (col < 3200) { int i = (col - 2560) >> 4; return 0.15811388300841897f * (i < 16 ? inv_s2 : 1.f); }
    {               int i = (col - 3200) >> 3;   return 0.20412414523193150f * (i < 16 ? inv_s3 : 1.f); }
}

// ---- prep: W2 -> w2f (fragment-order bf16, scale folded); W1 -> w1t; b2 -> b2s; zero acc ----
// w2f layout: [(c*4+t)*64 + lane] * 16 shorts:
//   first 8 = W2T[col=c*64+16t+(lane&15)][ (lane>>4)*8 + j ] ; next 8 = same col, k+32.
__global__ void prep_kernel(const float* __restrict__ w2,
                            const float* __restrict__ w1,
                            const float* __restrict__ bias2,
                            unsigned short* __restrict__ w2f,
                            unsigned short* __restrict__ w1t,
                            float* __restrict__ b2s,
                            float* __restrict__ zero_base) {
    const int b = blockIdx.x, tid = threadIdx.x;
    if (b >= 54) {
        // zero acc_g + cnt_g: 4489216 B = 280576 float4, 1096 blocks x 256
        size_t i = (size_t)(b - 54) * 256 + tid;
        ((float4*)zero_base)[i] = make_float4(0.f, 0.f, 0.f, 0.f);
        return;
    }
    __shared__ float tl[64 * 65];
    if (b < 53) {
        const int c0 = b * 64;
        for (int idx = tid; idx < 4096; idx += 256) {
            int k = idx >> 6, cc = idx & 63;
            tl[cc * 65 + k] = w2[k * WNUM + c0 + cc];     // coalesced over cc
        }
        __syncthreads();
        const int t = tid >> 6, lane = tid & 63, n = lane & 15, quad = lane >> 4;
        const int cc = 16 * t + n;
        const float sc = wscale(c0 + cc);
        unsigned short* dst = w2f + ((size_t)(b * 4 + t) * 64 + lane) * 16;
#pragma unroll
        for (int j = 0; j < 8; ++j) {
            dst[j]     = f2b(tl[cc * 65 + quad * 8 + j] * sc);
            dst[8 + j] = f2b(tl[cc * 65 + 32 + quad * 8 + j] * sc);
        }
        if (tid < 64) b2s[c0 + tid] = bias2[c0 + tid] * wscale(c0 + tid);
    } else {  // b == 53: W1 transpose -> bf16
        for (int idx = tid; idx < 4096; idx += 256) {
            int k = idx >> 6, j = idx & 63;
            tl[j * 65 + k] = w1[k * 64 + j];
        }
        __syncthreads();
        for (int idx = tid; idx < 4096; idx += 256) {
            int j = idx >> 6, k = idx & 63;
            w1t[j * 64 + k] = f2b(tl[j * 65 + k]);
        }
    }
}

// ---------------- fused main kernel: 64 edges per block, barrier-free K-loop ----------------
__global__ __launch_bounds__(256, 4)
void tpconv_main(const float* __restrict__ node_attr,
                 const int* __restrict__ edge_index,
                 const float* __restrict__ edge_attr,
                 const float* __restrict__ edge_sh,
                 const unsigned short* __restrict__ w1t,
                 const float* __restrict__ b1,
                 const unsigned short* __restrict__ w2f,
                 const float* __restrict__ b2s,
                 float* __restrict__ acc_g,
                 float* __restrict__ cnt_g) {
    // LDS 29696 B -> 4-5 blocks/CU:
    //  [0, 18944)      x gather bf16, 64 rows x stride 148 (row bank offsets all distinct)
    //  [18944, 28160)  h tile bf16, 64 x 72
    //  [28160, 29184)  sh f32, 64 x 4
    //  [29184, 29696)  src, dst
    //  after K-loop: [0, 18432) reused as f32 Y staging, 32 rows x 144 (two phases)
    __shared__ __align__(16) char smem[29696];
    unsigned short* x_lds = (unsigned short*)smem;
    unsigned short* h_lds = (unsigned short*)(smem + 18944);
    float* sh_lds = (float*)(smem + 28160);
    int* src_lds  = (int*)(smem + 29184);
    int* dst_lds  = (int*)(smem + 29440);

    const int tid  = threadIdx.x;
    const int lane = tid & 63;
    const int wv   = tid >> 6;
    const int n    = lane & 15;
    const int quad = lane >> 4;
    const int eb   = blockIdx.x * 64;

    // ---- indices, sh, counts ----
    if (tid < 64) {
        int s = edge_index[eb + tid];
        int d = edge_index[N_EDGES + eb + tid];
        src_lds[tid] = s;
        dst_lds[tid] = d;
        atomicAdd(&cnt_g[s], 1.0f);
        const float4 shv = *(const float4*)&edge_sh[(size_t)(eb + tid) * 4];
        sh_lds[tid * 4 + 0] = shv.x;
        sh_lds[tid * 4 + 1] = shv.y;
        sh_lds[tid * 4 + 2] = shv.z;
        sh_lds[tid * 4 + 3] = shv.w;
    }

    // ---- h = relu(ea @ W1 + b1) via MFMA -> h_lds ----
    {
        const float* ea = edge_attr + (size_t)(eb + wv * 16 + n) * 64 + quad * 8;
        s16x8 a0, a1;
#pragma unroll
        for (int j = 0; j < 8; ++j) {
            a0[j] = (short)f2b(ea[j]);
            a1[j] = (short)f2b(ea[32 + j]);
        }
        for (int ct = 0; ct < 4; ++ct) {
            int col = ct * 16 + n;
            const unsigned short* wp = w1t + col * 64;
            s16x8 bu0 = *(const s16x8*)&wp[quad * 8];
            s16x8 bu1 = *(const s16x8*)&wp[32 + quad * 8];
            f32x4 acc = {0.f, 0.f, 0.f, 0.f};
            acc = __builtin_amdgcn_mfma_f32_16x16x32_bf16(a0, bu0, acc, 0, 0, 0);
            acc = __builtin_amdgcn_mfma_f32_16x16x32_bf16(a1, bu1, acc, 0, 0, 0);
            float bias = b1[col];
            for (int r = 0; r < 4; ++r) {
                float hv = acc[r] + bias;
                hv = hv > 0.f ? hv : 0.f;
                h_lds[(wv * 16 + quad * 4 + r) * 72 + col] = f2b(hv);
            }
        }
    }
    __syncthreads();   // dst_lds visible

    // ---- x gather: node_attr[dst] (f32) -> bf16, stride 148 ----
    for (int idx = tid; idx < 64 * 34; idx += 256) {
        int e = idx / 34, seg = idx - e * 34;
        const float4 v = *(const float4*)(node_attr + (size_t)dst_lds[e] * FEAT + seg * 4);
        s16x4 pk;
        pk[0] = (short)f2b(v.x); pk[1] = (short)f2b(v.y);
        pk[2] = (short)f2b(v.z); pk[3] = (short)f2b(v.w);
        *(s16x4*)&x_lds[e * 148 + seg * 4] = pk;
    }
    __syncthreads();   // x, sh, h visible — LAST barrier before scatter

    // ---- per-lane state: lane owns edge eLoc ----
    const int eLoc = wv * 16 + n;
    const unsigned short* xr = &x_lds[eLoc * 148];
    const float sh0 = sh_lds[eLoc * 4 + 0];
    const float s1x = sh_lds[eLoc * 4 + 1];
    const float s1y = sh_lds[eLoc * 4 + 2];
    const float s1z = sh_lds[eLoc * 4 + 3];

    const unsigned short* hp = &h_lds[eLoc * 72];
    s16x8 h0 = *(const s16x8*)&hp[quad * 8];          // B[k=quad*8+j][n=edge]
    s16x8 h1 = *(const s16x8*)&hp[32 + quad * 8];

    float Y0e[4][2] = {};
    float Y1o[4][3] = {};
    float Y1e[4][3] = {};
    float Y0o[4]    = {};

    // fragment stream: one-ahead register prefetch, no LDS, no barriers
    const unsigned short* gbase = w2f + (size_t)lane * 16;
    s16x8 nf0, nf1;
    nf0 = *(const s16x8*)gbase;
    nf1 = *(const s16x8*)(gbase + 8);

#define PRE(t)                                                                  \
    s16x8 cf0 = nf0, cf1 = nf1;                                                 \
    {   int nid = c * 4 + (t) + 1; if (nid > 211) nid = 211;                    \
        const unsigned short* gp = gbase + (size_t)nid * 1024;                  \
        nf0 = *(const s16x8*)gp; nf1 = *(const s16x8*)(gp + 8); }               \
    f32x4 acc;                                                                  \
    {   const float4 bv = *(const float4*)(b2s + c * 64 + 16 * (t) + quad * 4); \
        acc[0] = bv.x; acc[1] = bv.y; acc[2] = bv.z; acc[3] = bv.w; }           \
    acc = __builtin_amdgcn_mfma_f32_16x16x32_bf16(cf0, h0, acc, 0, 0, 0);       \
    acc = __builtin_amdgcn_mfma_f32_16x16x32_bf16(cf1, h1, acc, 0, 0, 0);

    for (int c = 0; c < 53; ++c) {
        if (c < 24) {                                        // ---- 0e: col = i*32 + out
            float ov = 0.f;
#pragma unroll
            for (int t = 0; t < 4; ++t) {
                PRE(t)
                if ((t & 1) == 0) {
                    int i = 2 * c + (t >> 1);
                    if (c < 16) ov = b2f(xr[i]) * sh0;
                    else {
                        int ib = 32 + 3 * (i - 32);
                        ov = b2f(xr[ib]) * s1x + b2f(xr[ib + 1]) * s1y + b2f(xr[ib + 2]) * s1z;
                    }
                }
                const int kk = t & 1;
                Y0e[0][kk] += ov * acc[0];
                Y0e[1][kk] += ov * acc[1];
                Y0e[2][kk] += ov * acc[2];
                Y0e[3][kk] += ov * acc[3];
            }
        } else if (c < 40) {                                 // ---- 1o: col = 1536 + i*16 + out
#pragma unroll
            for (int t = 0; t < 4; ++t) {
                PRE(t)
                int i = 4 * (c - 24) + t;
                float o0, o1, o2;
                if (c < 32) {
                    float xv = b2f(xr[i]);
                    o0 = xv * s1x; o1 = xv * s1y; o2 = xv * s1z;
                } else if (c < 36) {
                    int ib = 32 + 3 * (i - 32);
                    o0 = b2f(xr[ib]) * sh0; o1 = b2f(xr[ib + 1]) * sh0; o2 = b2f(xr[ib + 2]) * sh0;
                } else {
                    int ib = 80 + 3 * (i - 48);
                    float a0v = b2f(xr[ib]), a1v = b2f(xr[ib + 1]), a2v = b2f(xr[ib + 2]);
                    o0 = a1v * s1z - a2v * s1y;
                    o1 = a2v * s1x - a0v * s1z;
                    o2 = a0v * s1y - a1v * s1x;
                }
#pragma unroll
                for (int r = 0; r < 4; ++r) {
                    float w = acc[r];
                    Y1o[r][0] += o0 * w; Y1o[r][1] += o1 * w; Y1o[r][2] += o2 * w;
                }
            }
        } else if (c < 50) {                                 // ---- 1e: col = 2560 + i*16 + out
#pragma unroll
            for (int t = 0; t < 4; ++t) {
                PRE(t)
                int i = 4 * (c - 40) + t;
                float o0, o1, o2;
                if (c < 44) {
                    int ib = 32 + 3 * i;
                    float a0v = b2f(xr[ib]), a1v = b2f(xr[ib + 1]), a2v = b2f(xr[ib + 2]);
                    o0 = a1v * s1z - a2v * s1y;
                    o1 = a2v * s1x - a0v * s1z;
                    o2 = a0v * s1y - a1v * s1x;
                } else if (c < 48) {
                    int ib = 80 + 3 * (i - 16);
                    o0 = b2f(xr[ib]) * sh0; o1 = b2f(xr[ib + 1]) * sh0; o2 = b2f(xr[ib + 2]) * sh0;
                } else {
                    float xv = b2f(xr[128 + (i - 32)]);
                    o0 = xv * s1x; o1 = xv * s1y; o2 = xv * s1z;
                }
#pragma unroll
                for (int r = 0; r < 4; ++r) {
                    float w = acc[r];
                    Y1e[r][0] += o0 * w; Y1e[r][1] += o1 * w; Y1e[r][2] += o2 * w;
                }
            }
        } else {                                             // ---- 0o: col = 3200 + i*8 + out
#pragma unroll
            for (int t = 0; t < 4; ++t) {
                PRE(t)
                float ov;
                if (c < 52) {
                    int i = 8 * (c - 50) + 2 * t + (quad >> 1);
                    int ib = 80 + 3 * i;
                    ov = b2f(xr[ib]) * s1x + b2f(xr[ib + 1]) * s1y + b2f(xr[ib + 2]) * s1z;
                } else {
                    int i2 = 2 * t + (quad >> 1);
                    ov = b2f(xr[128 + i2]) * sh0;
                }
                Y0o[0] += ov * acc[0];
                Y0o[1] += ov * acc[1];
                Y0o[2] += ov * acc[2];
                Y0o[3] += ov * acc[3];
            }
        }
    }
#undef PRE

    // ---- two-phase Y staging in LDS (reuse x region), then coalesced atomics ----
    __syncthreads();                          // all x reads done
    float* stage = (float*)smem;              // 32 rows x 144 f32 = 18432 B
    for (int ph = 0; ph < 2; ++ph) {
        if ((eLoc >> 5) == ph) {
            float* srow = stage + (eLoc & 31) * 144;
#pragma unroll
            for (int r = 0; r < 4; ++r) {
                int qr = quad * 4 + r;
                srow[qr]              = Y0e[r][0];
                srow[16 + qr]         = Y0e[r][1];
                srow[32 + qr * 3 + 0] = Y1o[r][0];
                srow[32 + qr * 3 + 1] = Y1o[r][1];
                srow[32 + qr * 3 + 2] = Y1o[r][2];
                srow[80 + qr * 3 + 0] = Y1e[r][0];
                srow[80 + qr * 3 + 1] = Y1e[r][1];
                srow[80 + qr * 3 + 2] = Y1e[r][2];
                srow[128 + (quad & 1) * 4 + r + (quad >> 1) * 8] = Y0o[r];
            }
        }
        __syncthreads();
        for (int j = 0; j < 8; ++j) {
            int e = ph * 32 + wv * 8 + j;
            float* dp = acc_g + (size_t)src_lds[e] * FEAT;
            const float* sr = stage + (wv * 8 + j) * 144;
            atomicAdd(dp + lane,      sr[lane]);
            atomicAdd(dp + 64 + lane, sr[64 + lane]);
            if (lane < 8)
                atomicAdd(dp + 128 + lane, sr[128 + lane] + sr[136 + lane]);
        }
        __syncthreads();
    }
}

// ---------------- finalize: mean + residual (fp32 out) ----------------
__global__ void finalize_kernel(const float* __restrict__ acc_g,
                                const float* __restrict__ cnt_g,
                                const float* __restrict__ node_attr,
                                float* __restrict__ out) {
    int idx = blockIdx.x * 256 + threadIdx.x;
    if (idx >= N_NODES * FEAT) return;
    int nn = idx / FEAT;
    float c = cnt_g[nn];
    out[idx] = acc_g[idx] / fmaxf(c, 1.0f) + node_attr[idx];
}

extern "C" void kernel_launch(void* const* d_in, const int* in_sizes, int n_in,
                              void* d_out, int out_size, void* d_ws, size_t ws_size,
                              hipStream_t stream) {
    const float* node_attr  = (const float*)d_in[0];
    const int*   edge_index = (const int*)d_in[1];
    const float* edge_attr  = (const float*)d_in[2];
    const float* edge_sh    = (const float*)d_in[3];
    const float* fc_w1      = (const float*)d_in[4];
    const float* fc_b1      = (const float*)d_in[5];
    const float* fc_w2      = (const float*)d_in[6];
    const float* fc_b2      = (const float*)d_in[7];
    float* out = (float*)d_out;

    char* ws = (char*)d_ws;
    float* acc_g = (float*)ws;                                      // 8192*136*4 = 4456448
    float* cnt_g = (float*)(ws + 4456448);                          // 32768 (zeroed with acc)
    unsigned short* w2f = (unsigned short*)(ws + 4489216);          // 53*4*64*16*2 = 434176
    unsigned short* w1t = (unsigned short*)(ws + 4489216 + 434176); // 8192
    float* b2s = (float*)(ws + 4489216 + 434176 + 8192);            // 13568

    prep_kernel<<<1150, 256, 0, stream>>>(fc_w2, fc_w1, fc_b2, w2f, w1t, b2s, acc_g);
    tpconv_main<<<1024, 256, 0, stream>>>(node_attr, edge_index, edge_attr, edge_sh,
                                          w1t, fc_b1, w2f, b2s, acc_g, cnt_g);
    finalize_kernel<<<(N_NODES * FEAT + 255) / 256, 256, 0, stream>>>(acc_g, cnt_g, node_attr, out);
}